// Round 8
// baseline (585.672 us; speedup 1.0000x reference)
//
#include <hip/hip_runtime.h>
#include <cstddef>
#include <cstdio>

// Problem constants: B=4, T=2048, C=1024, H=16, HS=64, FF=4096
#define Bn   4
#define Tn   2048
#define Cn   1024
#define Hn   16
#define HSn  64
#define FFn  4096
#define ROWS (Bn*Tn)        // 8192
#define QKVW (3*Cn)         // 3072

typedef __attribute__((ext_vector_type(8))) __bf16 bf16x8;
typedef __attribute__((ext_vector_type(4))) float f32x4;

// fp32 -> bf16 round-to-nearest-even, raw ushort storage
__device__ __forceinline__ unsigned short f2bf(float f){
  unsigned int u = __float_as_uint(f);
  unsigned int r = (u + 0x7fffu + ((u >> 16) & 1u)) >> 16;
  return (unsigned short)r;
}

// async global->LDS, 16B per lane; LDS dest = wave-uniform base + lane*16
#define GLD16(g, l) __builtin_amdgcn_global_load_lds( \
    (__attribute__((address_space(1))) void*)(void*)(g), \
    (__attribute__((address_space(3))) void*)(l), 16, 0, 0)

__device__ __forceinline__ float wave_sum_f(float v){
#pragma unroll
  for (int o = 32; o > 0; o >>= 1) v += __shfl_xor(v, o);
  return v;
}

// -------------------- LayerNorm: fp32 in -> bf16 out, one block per row -----
__global__ void ln_bf16(const float* __restrict__ x, const float* __restrict__ g,
                        const float* __restrict__ bb, unsigned short* __restrict__ y){
  const int row = blockIdx.x;
  const int tid = threadIdx.x;
  const float4 v = reinterpret_cast<const float4*>(x + (size_t)row * Cn)[tid];
  float s  = v.x + v.y + v.z + v.w;
  float ss = v.x*v.x + v.y*v.y + v.z*v.z + v.w*v.w;
  s = wave_sum_f(s); ss = wave_sum_f(ss);
  __shared__ float sm[4], sm2[4];
  const int w = tid >> 6, lane = tid & 63;
  if (lane == 0){ sm[w] = s; sm2[w] = ss; }
  __syncthreads();
  const float tot  = sm[0] + sm[1] + sm[2] + sm[3];
  const float tot2 = sm2[0] + sm2[1] + sm2[2] + sm2[3];
  const float mu = tot * (1.0f / Cn);
  const float rs = rsqrtf(tot2 * (1.0f / Cn) - mu * mu + 1e-5f);
  const float4 gv = reinterpret_cast<const float4*>(g)[tid];
  const float4 bv = reinterpret_cast<const float4*>(bb)[tid];
  ushort4 o;
  o.x = f2bf((v.x - mu) * rs * gv.x + bv.x);
  o.y = f2bf((v.y - mu) * rs * gv.y + bv.y);
  o.z = f2bf((v.z - mu) * rs * gv.z + bv.z);
  o.w = f2bf((v.w - mu) * rs * gv.w + bv.w);
  reinterpret_cast<ushort4*>(y + (size_t)row * Cn)[tid] = o;
}

// ---- generic transpose+cast: in fp32 [R][Cc] -> out bf16 [Cc][R] -----------
__global__ void transpose_cast(const float* __restrict__ in, unsigned short* __restrict__ out,
                               int R, int Cc){
  __shared__ float t[64][65];
  const int tid = threadIdx.x;
  const int r0 = blockIdx.y * 64, c0 = blockIdx.x * 64;
  const int rb = tid >> 6, cl = tid & 63;
#pragma unroll
  for (int j = 0; j < 16; ++j)
    t[rb + j*4][cl] = in[(size_t)(r0 + rb + j*4) * Cc + c0 + cl];
  __syncthreads();
#pragma unroll
  for (int j = 0; j < 16; ++j)
    out[(size_t)(c0 + rb + j*4) * R + r0 + cl] = f2bf(t[cl][rb + j*4]);
}

// ---- QKV weights [H,C,HS] -> Wrt bf16 [N=3C][K=C]; row j = sec*C + h*64 + d
__global__ void repack_qkv_t(const float* __restrict__ Wq, const float* __restrict__ Wk,
                             const float* __restrict__ Wv, unsigned short* __restrict__ Wrt){
  __shared__ float t[64][65];
  const int tid = threadIdx.x;
  const int kb = blockIdx.x * 64;            // k tile
  const int hh = blockIdx.y;                 // 0..47
  const int sec = hh >> 4, h = hh & 15;
  const float* W = (sec == 0) ? Wq : ((sec == 1) ? Wk : Wv);
  const int rb = tid >> 6, dl = tid & 63;
#pragma unroll
  for (int j = 0; j < 16; ++j)
    t[rb + j*4][dl] = W[h * (Cn*HSn) + (size_t)(kb + rb + j*4) * HSn + dl];
  __syncthreads();
#pragma unroll
  for (int j = 0; j < 16; ++j)
    Wrt[(size_t)(sec*Cn + h*64 + rb + j*4) * Cn + kb + dl] = f2bf(t[dl][rb + j*4]);
}

// ---- bf16 MFMA GEMM, 256x256 tile, counted-vmcnt ring pipeline -------------
// (R4-verified.)  512 threads = 8 waves (2M x 4N), per-wave 128x64 out.
// BK=64. 4-slot ring of 16KB half-tiles per operand; tile t -> slots
// {2t,2t+1}&3. Per K-tile: stage t+1 (8 GLD16) -> vmcnt(8) -> barrier
// -> 64 MFMA -> barrier.  Swizzle: granule (row,k8) holds global k8^(row&7);
// read applies same XOR.  Grid: bijective XCD remap (nwg % 8 == 0).
template<int RELU, int OUT_BF16>
__global__ __launch_bounds__(512, 2)
void gemm256(const unsigned short* __restrict__ A, const unsigned short* __restrict__ Bt,
             void* __restrict__ Cout, int M, int N, int K,
             const float* __restrict__ bias, const float* __restrict__ resid){
  __shared__ __align__(16) unsigned short As[4 * 8192];   // 64 KB
  __shared__ __align__(16) unsigned short Bs[4 * 8192];   // 64 KB
  const int tid  = threadIdx.x;
  const int wid  = tid >> 6, lane = tid & 63;
  const int wm   = wid >> 2, wn = wid & 3;
  const int fr   = lane & 15, Lq = lane >> 4;

  const int id  = blockIdx.x + gridDim.x * blockIdx.y;
  const int Nbn = gridDim.x;
  const int cpx = (gridDim.x * gridDim.y) >> 3;
  const int wg  = (id & 7) * cpx + (id >> 3);
  const int bm  = wg / Nbn;
  const int bn  = wg - bm * Nbn;

  const int srow  = wid * 8 + (lane >> 3);
  const int skoff = (((lane & 7) ^ (srow & 7)) * 8);
  const unsigned short* Abase = A  + (size_t)(bm * 256 + srow) * K + skoff;
  const unsigned short* Bbase = Bt + (size_t)(bn * 256 + srow) * K + skoff;

  auto stA = [&](int t, int h){
    const unsigned short* g0 = Abase + (size_t)h * 128 * K + (size_t)t * 64;
    unsigned short* l0 = As + (((2*t + h) & 3) * 8192) + wid * 512;
    GLD16(g0, l0);
    GLD16(g0 + (size_t)64 * K, l0 + 4096);
  };
  auto stB = [&](int t, int h){
    const unsigned short* g0 = Bbase + (size_t)h * 128 * K + (size_t)t * 64;
    unsigned short* l0 = Bs + (((2*t + h) & 3) * 8192) + wid * 512;
    GLD16(g0, l0);
    GLD16(g0 + (size_t)64 * K, l0 + 4096);
  };

  f32x4 acc[8][4] = {};
  const int NT = K >> 6;

  stA(0, 0); stA(0, 1); stB(0, 0); stB(0, 1);

  for (int t = 0; t < NT; ++t){
    const unsigned short* aS = As + (((2*t + wm) & 3) * 8192);
    const unsigned short* bS = Bs + (((2*t + (wn >> 1)) & 3) * 8192)
                                  + ((wn & 1) * 64) * 64;
    const bool pf = (t + 1 < NT);

    if (pf){ stA(t+1, 0); stA(t+1, 1); stB(t+1, 0); stB(t+1, 1); }
    __builtin_amdgcn_sched_barrier(0);
    if (pf) asm volatile("s_waitcnt vmcnt(8)");
    else    asm volatile("s_waitcnt vmcnt(0)");
    __builtin_amdgcn_s_barrier();

#pragma unroll
    for (int kk = 0; kk < 2; ++kk){
      const int kx = (((kk*4) + Lq) ^ (fr & 7)) * 8;
      bf16x8 bfv[4], af[4];
#pragma unroll
      for (int ni = 0; ni < 4; ++ni)
        bfv[ni] = *reinterpret_cast<const bf16x8*>(&bS[(ni*16 + fr) * 64 + kx]);
#pragma unroll
      for (int m2 = 0; m2 < 4; ++m2)
        af[m2] = *reinterpret_cast<const bf16x8*>(&aS[(m2*16 + fr) * 64 + kx]);
#pragma unroll
      for (int m2 = 0; m2 < 4; ++m2)
#pragma unroll
        for (int ni = 0; ni < 4; ++ni)
          acc[m2][ni] = __builtin_amdgcn_mfma_f32_16x16x32_bf16(
              af[m2], bfv[ni], acc[m2][ni], 0, 0, 0);
#pragma unroll
      for (int m2 = 0; m2 < 4; ++m2)
        af[m2] = *reinterpret_cast<const bf16x8*>(&aS[((4+m2)*16 + fr) * 64 + kx]);
#pragma unroll
      for (int m2 = 0; m2 < 4; ++m2)
#pragma unroll
        for (int ni = 0; ni < 4; ++ni)
          acc[4+m2][ni] = __builtin_amdgcn_mfma_f32_16x16x32_bf16(
              af[m2], bfv[ni], acc[4+m2][ni], 0, 0, 0);
    }
    __builtin_amdgcn_sched_barrier(0);
    __builtin_amdgcn_s_barrier();
  }

  const int lc = fr, lr4 = Lq * 4;
#pragma unroll
  for (int ni = 0; ni < 4; ++ni){
    const int col = bn*256 + wn*64 + ni*16 + lc;
    const float bv = bias ? bias[col] : 0.f;
#pragma unroll
    for (int mi = 0; mi < 8; ++mi){
      const int rowb = bm*256 + wm*128 + mi*16 + lr4;
#pragma unroll
      for (int r = 0; r < 4; ++r){
        float v = acc[mi][ni][r] + bv;
        if (RELU) v = fmaxf(v, 0.f);
        if (resid) v += resid[(size_t)(rowb + r) * N + col];
        if (OUT_BF16)
          ((unsigned short*)Cout)[(size_t)(rowb + r) * N + col] = f2bf(v);
        else
          ((float*)Cout)[(size_t)(rowb + r) * N + col] = v;
      }
    }
  }
}

// ---- bf16 MFMA GEMM, 128x128 tile, counted-vmcnt double-buffer (R5) --------
// For N=1024 GEMMs (proj, FF2): grid 8x64 = 512 blocks = 2/CU.
template<int RELU, int OUT_BF16>
__global__ __launch_bounds__(256, 2)
void gemm128ring(const unsigned short* __restrict__ A, const unsigned short* __restrict__ Bt,
                 void* __restrict__ Cout, int M, int N, int K,
                 const float* __restrict__ bias, const float* __restrict__ resid){
  __shared__ __align__(16) unsigned short As[2 * 8192];   // 32 KB
  __shared__ __align__(16) unsigned short Bs[2 * 8192];   // 32 KB
  const int tid  = threadIdx.x;
  const int wave = tid >> 6, lane = tid & 63;
  const int wm   = wave >> 1, wn = wave & 1;
  const int fr   = lane & 15, Lq = lane >> 4;

  const int id  = blockIdx.x + gridDim.x * blockIdx.y;
  const int Nbn = gridDim.x;
  const int cpx = (gridDim.x * gridDim.y) >> 3;
  const int wg  = (id & 7) * cpx + (id >> 3);
  const int bm  = wg / Nbn;
  const int bn  = wg - bm * Nbn;

  const int srow  = tid >> 3;                       // 0..31
  const int skoff = (((tid & 7) ^ (srow & 7)) * 8);
  const unsigned short* Abase = A  + (size_t)(bm * 128 + srow) * K + skoff;
  const unsigned short* Bbase = Bt + (size_t)(bn * 128 + srow) * K + skoff;

  auto stA = [&](int t){
    const unsigned short* g0 = Abase + (size_t)t * 64;
    unsigned short* l0 = As + ((t & 1) * 8192) + tid * 8;
#pragma unroll
    for (int j = 0; j < 4; ++j)
      GLD16(g0 + (size_t)(j*32) * K, l0 + j*2048);
  };
  auto stB = [&](int t){
    const unsigned short* g0 = Bbase + (size_t)t * 64;
    unsigned short* l0 = Bs + ((t & 1) * 8192) + tid * 8;
#pragma unroll
    for (int j = 0; j < 4; ++j)
      GLD16(g0 + (size_t)(j*32) * K, l0 + j*2048);
  };

  f32x4 acc[4][4] = {};
  const int NT = K >> 6;

  stA(0); stB(0);

  for (int t = 0; t < NT; ++t){
    const unsigned short* aS = As + ((t & 1) * 8192);
    const unsigned short* bS = Bs + ((t & 1) * 8192);
    const bool pf = (t + 1 < NT);

    if (pf){ stA(t+1); stB(t+1); }
    __builtin_amdgcn_sched_barrier(0);
    if (pf) asm volatile("s_waitcnt vmcnt(8)");
    else    asm volatile("s_waitcnt vmcnt(0)");
    __builtin_amdgcn_s_barrier();

#pragma unroll
    for (int kk = 0; kk < 2; ++kk){
      const int kx = (((kk*4) + Lq) ^ (fr & 7)) * 8;
      bf16x8 bfv[4], af[4];
#pragma unroll
      for (int ni = 0; ni < 4; ++ni)
        bfv[ni] = *reinterpret_cast<const bf16x8*>(&bS[(wn*64 + ni*16 + fr) * 64 + kx]);
#pragma unroll
      for (int mi = 0; mi < 4; ++mi)
        af[mi] = *reinterpret_cast<const bf16x8*>(&aS[(wm*64 + mi*16 + fr) * 64 + kx]);
#pragma unroll
      for (int mi = 0; mi < 4; ++mi)
#pragma unroll
        for (int ni = 0; ni < 4; ++ni)
          acc[mi][ni] = __builtin_amdgcn_mfma_f32_16x16x32_bf16(
              af[mi], bfv[ni], acc[mi][ni], 0, 0, 0);
    }
    __builtin_amdgcn_sched_barrier(0);
    __builtin_amdgcn_s_barrier();
  }

  const int lc = fr, lr4 = Lq * 4;
#pragma unroll
  for (int ni = 0; ni < 4; ++ni){
    const int col = bn*128 + wn*64 + ni*16 + lc;
    const float bv = bias ? bias[col] : 0.f;
#pragma unroll
    for (int mi = 0; mi < 4; ++mi){
      const int rowb = bm*128 + wm*64 + mi*16 + lr4;
#pragma unroll
      for (int r = 0; r < 4; ++r){
        float v = acc[mi][ni][r] + bv;
        if (RELU) v = fmaxf(v, 0.f);
        if (resid) v += resid[(size_t)(rowb + r) * N + col];
        if (OUT_BF16)
          ((unsigned short*)Cout)[(size_t)(rowb + r) * N + col] = f2bf(v);
        else
          ((float*)Cout)[(size_t)(rowb + r) * N + col] = v;
      }
    }
  }
}

// ---- blockify K/V from qkv into MFMA-friendly blocked global layouts -------
__global__ void blockify_kv(const unsigned short* __restrict__ qkv,
                            unsigned short* __restrict__ Kb,
                            unsigned short* __restrict__ Vb){
  const int st = blockIdx.x, h = blockIdx.y, b = blockIdx.z;
  const int tid = threadIdx.x;
  const size_t base = ((size_t)(b*Hn + h)*32 + st) * 4096;
#pragma unroll
  for (int it = 0; it < 2; ++it){
    const int idx = it*256 + tid;
    const int s = idx >> 3, d8 = idx & 7;
    const uint4 v = *reinterpret_cast<const uint4*>(
        qkv + (size_t)(b*Tn + st*64 + s)*QKVW + Cn + h*64 + d8*8);
    *reinterpret_cast<uint4*>(Kb + base + d8*512 + ((s ^ d8) * 8)) = v;
  }
#pragma unroll
  for (int it = 0; it < 2; ++it){
    const int idx = it*256 + tid;
    const int d = idx & 63, s8 = idx >> 6;
    unsigned short tmp[8];
#pragma unroll
    for (int j = 0; j < 8; ++j)
      tmp[j] = qkv[(size_t)(b*Tn + st*64 + s8*8 + j)*QKVW + 2*Cn + h*64 + d];
    ushort4 lo, hi;
    lo.x = tmp[0]; lo.y = tmp[1]; lo.z = tmp[2]; lo.w = tmp[3];
    hi.x = tmp[4]; hi.y = tmp[5]; hi.z = tmp[6]; hi.w = tmp[7];
    *reinterpret_cast<ushort4*>(Vb + base + s8*512 + ((d ^ s8) * 8))     = lo;
    *reinterpret_cast<ushort4*>(Vb + base + s8*512 + ((d ^ s8) * 8) + 4) = hi;
  }
}

// -------------------- MFMA flash attention v4 (R6 rewrite) ------------------
// De-coupled waves: NO block barriers, NO LDS K/V staging. K/V fragments are
// read directly from the blocked+swizzled global Kb/Vb (L2-resident: one
// head's K+V = 512KB, 8 heads/XCD = 4MB L2; grid id&7 == bh&7 pins all
// q-groups of a head to one XCD). Rationale (R6 counters): the barriered
// v3 ran ~1 active wave/SIMD for most rounds (light-strip waves finish
// early) -> latency-bound, MfmaUtil 13.7%. Independent waves overlap freely.
// Geometry: 256-thread blocks (4 waves), grid (64 bh, 8 qg).
// Wave w of block qg owns qblk in {qg, qg+8, 23-qg, 31-qg} -> per-block work
// = 66 tile-iters for every block (static balance); waves retire
// independently (dynamic balance).  P-table per-wave in LDS (no sync).
__global__ __launch_bounds__(256, 2)
void attn_mfma4(const unsigned short* __restrict__ qkv,
                const unsigned short* __restrict__ Kb,
                const unsigned short* __restrict__ Vb,
                unsigned short* __restrict__ O){
  __shared__ __align__(16) unsigned short Pt[4][16][72];  // per-wave [q][s], pad 72

  const int bh = blockIdx.x;
  const int b = bh >> 4, h = bh & 15;
  const int qg = blockIdx.y;                 // 0..7
  const int tid = threadIdx.x;
  const int wv = tid >> 6, l = tid & 63;
  const int qblk = (wv == 0) ? qg : (wv == 1) ? (qg + 8)
                 : (wv == 2) ? (23 - qg) : (31 - qg);
  const int Lq = l >> 4, fr = l & 15;

  const size_t kvbase = ((size_t)(b*Hn + h) * 32) * 4096;

  union U { uint4 u; bf16x8 v; };
  // Q fragments (B-operand): lane n=fr -> q = qblk*64 + f*16 + fr
  U qf[4][2];
  const unsigned short* Qbase = qkv + ((size_t)(b*Tn + qblk*64)) * QKVW + h*64;
#pragma unroll
  for (int f = 0; f < 4; ++f){
    const unsigned short* qr = Qbase + (size_t)(f*16 + fr) * QKVW + Lq*8;
    qf[f][0].u = *reinterpret_cast<const uint4*>(qr);
    qf[f][1].u = *reinterpret_cast<const uint4*>(qr + 32);
  }

  f32x4 Oa[4][4] = {};                       // [db][f]
  float lsum[4] = {0.f, 0.f, 0.f, 0.f};
  const float C1 = 0.18033688011112042f;     // 0.125 * log2(e)
  const float C2 = 28.853900817779268f;      // 20 * log2(e) (fixed-max offset)

  for (int st = 0; st <= qblk; ++st){
    const unsigned short* Kt = Kb + kvbase + (size_t)st * 4096;
    const unsigned short* Vt = Vb + kvbase + (size_t)st * 4096;

    // K fragments (A-operand: m=s-row, k=d) straight from L2
    U k0[4], k1[4];
#pragma unroll
    for (int sb = 0; sb < 4; ++sb){
      const int s = sb*16 + fr;
      k0[sb].u = *reinterpret_cast<const uint4*>(&Kt[ Lq   *512 + ((s ^  Lq   ) * 8)]);
      k1[sb].u = *reinterpret_cast<const uint4*>(&Kt[(4+Lq)*512 + ((s ^ (4+Lq)) * 8)]);
    }
    // V fragments (A-operand: m=d-row, k=s) straight from L2
    U v0[4], v1[4];
#pragma unroll
    for (int db = 0; db < 4; ++db){
      const int d = db*16 + fr;
      v0[db].u = *reinterpret_cast<const uint4*>(&Vt[ Lq   *512 + ((d ^  Lq   ) * 8)]);
      v1[db].u = *reinterpret_cast<const uint4*>(&Vt[(4+Lq)*512 + ((d ^ (4+Lq)) * 8)]);
    }

    const bool diag = (st == qblk);
#pragma unroll
    for (int f = 0; f < 4; ++f){
      // ---- S^T = K Q^T : lane holds col q = f*16+fr, row s = sb*16+Lq*4+r ----
      f32x4 S[4];
#pragma unroll
      for (int sb = 0; sb < 4; ++sb){
        f32x4 z = {0.f, 0.f, 0.f, 0.f};
        z     = __builtin_amdgcn_mfma_f32_16x16x32_bf16(k0[sb].v, qf[f][0].v, z, 0, 0, 0);
        S[sb] = __builtin_amdgcn_mfma_f32_16x16x32_bf16(k1[sb].v, qf[f][1].v, z, 0, 0, 0);
      }
      // ---- fixed-max softmax (per-lane) + pack P into per-wave LDS table ----
#pragma unroll
      for (int sb = 0; sb < 4; ++sb){
        float p0 = exp2f(fmaf(S[sb][0], C1, -C2));
        float p1 = exp2f(fmaf(S[sb][1], C1, -C2));
        float p2 = exp2f(fmaf(S[sb][2], C1, -C2));
        float p3 = exp2f(fmaf(S[sb][3], C1, -C2));
        if (diag){
          const int s0 = sb*16 + Lq*4, q = f*16 + fr;
          if (s0 + 0 > q) p0 = 0.f;
          if (s0 + 1 > q) p1 = 0.f;
          if (s0 + 2 > q) p2 = 0.f;
          if (s0 + 3 > q) p3 = 0.f;
        }
        lsum[f] += (p0 + p1) + (p2 + p3);
        const unsigned int pk0 = (unsigned int)f2bf(p0) | ((unsigned int)f2bf(p1) << 16);
        const unsigned int pk1 = (unsigned int)f2bf(p2) | ((unsigned int)f2bf(p3) << 16);
        *reinterpret_cast<uint2*>(&Pt[wv][fr][sb*16 + Lq*4]) = make_uint2(pk0, pk1);
      }
      // ---- O^T += V^T P^T : B-operand P (k=s, n=q=fr) ----
      U pf0, pf1;
      pf0.u = *reinterpret_cast<const uint4*>(&Pt[wv][fr][Lq*8]);
      pf1.u = *reinterpret_cast<const uint4*>(&Pt[wv][fr][32 + Lq*8]);
#pragma unroll
      for (int db = 0; db < 4; ++db){
        Oa[db][f] = __builtin_amdgcn_mfma_f32_16x16x32_bf16(v0[db].v, pf0.v, Oa[db][f], 0, 0, 0);
        Oa[db][f] = __builtin_amdgcn_mfma_f32_16x16x32_bf16(v1[db].v, pf1.v, Oa[db][f], 0, 0, 0);
      }
    }
  }

  // ---- epilogue: reduce l across the 4 quads holding the same q ----
#pragma unroll
  for (int f = 0; f < 4; ++f){
    float s = lsum[f];
    s += __shfl_xor(s, 16);
    s += __shfl_xor(s, 32);
    const float inv = 1.0f / s;
    const size_t orow = (size_t)(b*Tn + qblk*64 + f*16 + fr);
#pragma unroll
    for (int db = 0; db < 4; ++db){
      ushort4 o;
      o.x = f2bf(Oa[db][f][0] * inv);
      o.y = f2bf(Oa[db][f][1] * inv);
      o.z = f2bf(Oa[db][f][2] * inv);
      o.w = f2bf(Oa[db][f][3] * inv);
      *reinterpret_cast<ushort4*>(&O[orow*Cn + h*64 + db*16 + Lq*4]) = o;
    }
  }
}

// -------------------- launcher ---------------------------------------------
extern "C" void kernel_launch(void* const* d_in, const int* in_sizes, int n_in,
                              void* d_out, int out_size, void* d_ws, size_t ws_size,
                              hipStream_t stream){
  const float* x     = (const float*)d_in[0];
  const float* Wq    = (const float*)d_in[1];
  const float* Wk    = (const float*)d_in[2];
  const float* Wv    = (const float*)d_in[3];
  const float* Wproj = (const float*)d_in[4];
  const float* bproj = (const float*)d_in[5];
  const float* W1    = (const float*)d_in[6];
  const float* b1    = (const float*)d_in[7];
  const float* W2    = (const float*)d_in[8];
  const float* b2    = (const float*)d_in[9];
  const float* ln1_g = (const float*)d_in[10];
  const float* ln1_b = (const float*)d_in[11];
  const float* ln2_g = (const float*)d_in[12];
  const float* ln2_b = (const float*)d_in[13];
  float* out = (float*)d_out;

  const size_t MB = 1024ull * 1024ull;
  if (ws_size < 192ull * MB){
    fprintf(stderr, "kernel_launch: need 192MB workspace, got %zu\n", ws_size);
    return;
  }
  char* ws = (char*)d_ws;
  float*          x1    = (float*)(ws + 0);
  unsigned short* h     = (unsigned short*)(ws + 32 * MB);
  unsigned short* qkvb  = (unsigned short*)(ws + 48 * MB);
  unsigned short* ff1   = (unsigned short*)(ws + 48 * MB);   // after attn
  unsigned short* Kb    = (unsigned short*)(ws + 96 * MB);
  unsigned short* Vb    = (unsigned short*)(ws + 112 * MB);
  unsigned short* Ob    = (unsigned short*)(ws + 128 * MB);
  unsigned short* Wrt   = (unsigned short*)(ws + 144 * MB);
  unsigned short* Wpt   = (unsigned short*)(ws + 150 * MB);
  unsigned short* W1t   = (unsigned short*)(ws + 152 * MB);
  unsigned short* W2t   = (unsigned short*)(ws + 160 * MB);

  // weight prep (bf16, B^T layout)
  repack_qkv_t<<<dim3(Cn/64, 3*Hn), 256, 0, stream>>>(Wq, Wk, Wv, Wrt);
  transpose_cast<<<dim3(Cn/64,  Cn/64),  256, 0, stream>>>(Wproj, Wpt, Cn,  Cn);
  transpose_cast<<<dim3(FFn/64, Cn/64),  256, 0, stream>>>(W1,    W1t, Cn,  FFn);
  transpose_cast<<<dim3(Cn/64,  FFn/64), 256, 0, stream>>>(W2,    W2t, FFn, Cn);

  // 1. h = LN1(x)  (bf16)
  ln_bf16<<<ROWS, 256, 0, stream>>>(x, ln1_g, ln1_b, h);
  // 2. qkv = h @ Wr  (bf16 out)  [256^2 counted-vmcnt]
  gemm256<0,1><<<dim3(QKVW/256, ROWS/256), 512, 0, stream>>>(
      h, Wrt, qkvb, ROWS, QKVW, Cn, nullptr, nullptr);
  // 3. blocked+swizzled K/V layouts for attention direct-read
  blockify_kv<<<dim3(Tn/64, Hn, Bn), 256, 0, stream>>>(qkvb, Kb, Vb);
  // 4. MFMA flash attention v4 (de-coupled waves, L2 direct-read) -> Ob
  attn_mfma4<<<dim3(64, 8), 256, 0, stream>>>(qkvb, Kb, Vb, Ob);
  // 5. x1 = x + Ob @ Wproj + bproj  (fp32)  [128^2 counted-vmcnt ring]
  gemm128ring<0,0><<<dim3(Cn/128, ROWS/128), 256, 0, stream>>>(
      Ob, Wpt, x1, ROWS, Cn, Cn, bproj, x);
  // 6. h2 = LN2(x1)  (bf16)
  ln_bf16<<<ROWS, 256, 0, stream>>>(x1, ln2_g, ln2_b, h);
  // 7. ff1 = relu(h2 @ W1 + b1)  (bf16)  [256^2 counted-vmcnt]
  gemm256<1,1><<<dim3(FFn/256, ROWS/256), 512, 0, stream>>>(
      h, W1t, ff1, ROWS, FFn, Cn, b1, nullptr);
  // 8. out = x1 + ff1 @ W2 + b2  (fp32)  [128^2 counted-vmcnt ring]
  gemm128ring<0,0><<<dim3(Cn/128, ROWS/128), 256, 0, stream>>>(
      ff1, W2t, out, ROWS, Cn, FFn, b2, x1);
}

// Round 9
// 559.171 us; speedup vs baseline: 1.0474x; 1.0474x over previous
//
#include <hip/hip_runtime.h>
#include <cstddef>
#include <cstdio>

// Problem constants: B=4, T=2048, C=1024, H=16, HS=64, FF=4096
#define Bn   4
#define Tn   2048
#define Cn   1024
#define Hn   16
#define HSn  64
#define FFn  4096
#define ROWS (Bn*Tn)        // 8192
#define QKVW (3*Cn)         // 3072

typedef __attribute__((ext_vector_type(8))) __bf16 bf16x8;
typedef __attribute__((ext_vector_type(4))) float f32x4;

// fp32 -> bf16 round-to-nearest-even, raw ushort storage
__device__ __forceinline__ unsigned short f2bf(float f){
  unsigned int u = __float_as_uint(f);
  unsigned int r = (u + 0x7fffu + ((u >> 16) & 1u)) >> 16;
  return (unsigned short)r;
}

// async global->LDS, 16B per lane; LDS dest = wave-uniform base + lane*16
#define GLD16(g, l) __builtin_amdgcn_global_load_lds( \
    (__attribute__((address_space(1))) void*)(void*)(g), \
    (__attribute__((address_space(3))) void*)(l), 16, 0, 0)

__device__ __forceinline__ float wave_sum_f(float v){
#pragma unroll
  for (int o = 32; o > 0; o >>= 1) v += __shfl_xor(v, o);
  return v;
}

// -------------------- LayerNorm: fp32 in -> bf16 out, one block per row -----
__global__ void ln_bf16(const float* __restrict__ x, const float* __restrict__ g,
                        const float* __restrict__ bb, unsigned short* __restrict__ y){
  const int row = blockIdx.x;
  const int tid = threadIdx.x;
  const float4 v = reinterpret_cast<const float4*>(x + (size_t)row * Cn)[tid];
  float s  = v.x + v.y + v.z + v.w;
  float ss = v.x*v.x + v.y*v.y + v.z*v.z + v.w*v.w;
  s = wave_sum_f(s); ss = wave_sum_f(ss);
  __shared__ float sm[4], sm2[4];
  const int w = tid >> 6, lane = tid & 63;
  if (lane == 0){ sm[w] = s; sm2[w] = ss; }
  __syncthreads();
  const float tot  = sm[0] + sm[1] + sm[2] + sm[3];
  const float tot2 = sm2[0] + sm2[1] + sm2[2] + sm2[3];
  const float mu = tot * (1.0f / Cn);
  const float rs = rsqrtf(tot2 * (1.0f / Cn) - mu * mu + 1e-5f);
  const float4 gv = reinterpret_cast<const float4*>(g)[tid];
  const float4 bv = reinterpret_cast<const float4*>(bb)[tid];
  ushort4 o;
  o.x = f2bf((v.x - mu) * rs * gv.x + bv.x);
  o.y = f2bf((v.y - mu) * rs * gv.y + bv.y);
  o.z = f2bf((v.z - mu) * rs * gv.z + bv.z);
  o.w = f2bf((v.w - mu) * rs * gv.w + bv.w);
  reinterpret_cast<ushort4*>(y + (size_t)row * Cn)[tid] = o;
}

// ---- generic transpose+cast: in fp32 [R][Cc] -> out bf16 [Cc][R] -----------
__global__ void transpose_cast(const float* __restrict__ in, unsigned short* __restrict__ out,
                               int R, int Cc){
  __shared__ float t[64][65];
  const int tid = threadIdx.x;
  const int r0 = blockIdx.y * 64, c0 = blockIdx.x * 64;
  const int rb = tid >> 6, cl = tid & 63;
#pragma unroll
  for (int j = 0; j < 16; ++j)
    t[rb + j*4][cl] = in[(size_t)(r0 + rb + j*4) * Cc + c0 + cl];
  __syncthreads();
#pragma unroll
  for (int j = 0; j < 16; ++j)
    out[(size_t)(c0 + rb + j*4) * R + r0 + cl] = f2bf(t[cl][rb + j*4]);
}

// ---- QKV weights [H,C,HS] -> Wrt bf16 [N=3C][K=C]; row j = sec*C + h*64 + d
__global__ void repack_qkv_t(const float* __restrict__ Wq, const float* __restrict__ Wk,
                             const float* __restrict__ Wv, unsigned short* __restrict__ Wrt){
  __shared__ float t[64][65];
  const int tid = threadIdx.x;
  const int kb = blockIdx.x * 64;            // k tile
  const int hh = blockIdx.y;                 // 0..47
  const int sec = hh >> 4, h = hh & 15;
  const float* W = (sec == 0) ? Wq : ((sec == 1) ? Wk : Wv);
  const int rb = tid >> 6, dl = tid & 63;
#pragma unroll
  for (int j = 0; j < 16; ++j)
    t[rb + j*4][dl] = W[h * (Cn*HSn) + (size_t)(kb + rb + j*4) * HSn + dl];
  __syncthreads();
#pragma unroll
  for (int j = 0; j < 16; ++j)
    Wrt[(size_t)(sec*Cn + h*64 + rb + j*4) * Cn + kb + dl] = f2bf(t[dl][rb + j*4]);
}

// ---- bf16 MFMA GEMM, 256x256 tile, counted-vmcnt ring pipeline -------------
// (R4-verified.)  512 threads = 8 waves (2M x 4N), per-wave 128x64 out.
// BK=64. 4-slot ring of 16KB half-tiles per operand; tile t -> slots
// {2t,2t+1}&3. Per K-tile: stage t+1 (8 GLD16) -> vmcnt(8) -> barrier
// -> 64 MFMA -> barrier.  Swizzle: granule (row,k8) holds global k8^(row&7);
// read applies same XOR.  Grid: bijective XCD remap (nwg % 8 == 0).
template<int RELU, int OUT_BF16>
__global__ __launch_bounds__(512, 2)
void gemm256(const unsigned short* __restrict__ A, const unsigned short* __restrict__ Bt,
             void* __restrict__ Cout, int M, int N, int K,
             const float* __restrict__ bias, const float* __restrict__ resid){
  __shared__ __align__(16) unsigned short As[4 * 8192];   // 64 KB
  __shared__ __align__(16) unsigned short Bs[4 * 8192];   // 64 KB
  const int tid  = threadIdx.x;
  const int wid  = tid >> 6, lane = tid & 63;
  const int wm   = wid >> 2, wn = wid & 3;
  const int fr   = lane & 15, Lq = lane >> 4;

  const int id  = blockIdx.x + gridDim.x * blockIdx.y;
  const int Nbn = gridDim.x;
  const int cpx = (gridDim.x * gridDim.y) >> 3;
  const int wg  = (id & 7) * cpx + (id >> 3);
  const int bm  = wg / Nbn;
  const int bn  = wg - bm * Nbn;

  const int srow  = wid * 8 + (lane >> 3);
  const int skoff = (((lane & 7) ^ (srow & 7)) * 8);
  const unsigned short* Abase = A  + (size_t)(bm * 256 + srow) * K + skoff;
  const unsigned short* Bbase = Bt + (size_t)(bn * 256 + srow) * K + skoff;

  auto stA = [&](int t, int h){
    const unsigned short* g0 = Abase + (size_t)h * 128 * K + (size_t)t * 64;
    unsigned short* l0 = As + (((2*t + h) & 3) * 8192) + wid * 512;
    GLD16(g0, l0);
    GLD16(g0 + (size_t)64 * K, l0 + 4096);
  };
  auto stB = [&](int t, int h){
    const unsigned short* g0 = Bbase + (size_t)h * 128 * K + (size_t)t * 64;
    unsigned short* l0 = Bs + (((2*t + h) & 3) * 8192) + wid * 512;
    GLD16(g0, l0);
    GLD16(g0 + (size_t)64 * K, l0 + 4096);
  };

  f32x4 acc[8][4] = {};
  const int NT = K >> 6;

  stA(0, 0); stA(0, 1); stB(0, 0); stB(0, 1);

  for (int t = 0; t < NT; ++t){
    const unsigned short* aS = As + (((2*t + wm) & 3) * 8192);
    const unsigned short* bS = Bs + (((2*t + (wn >> 1)) & 3) * 8192)
                                  + ((wn & 1) * 64) * 64;
    const bool pf = (t + 1 < NT);

    if (pf){ stA(t+1, 0); stA(t+1, 1); stB(t+1, 0); stB(t+1, 1); }
    __builtin_amdgcn_sched_barrier(0);
    if (pf) asm volatile("s_waitcnt vmcnt(8)");
    else    asm volatile("s_waitcnt vmcnt(0)");
    __builtin_amdgcn_s_barrier();

#pragma unroll
    for (int kk = 0; kk < 2; ++kk){
      const int kx = (((kk*4) + Lq) ^ (fr & 7)) * 8;
      bf16x8 bfv[4], af[4];
#pragma unroll
      for (int ni = 0; ni < 4; ++ni)
        bfv[ni] = *reinterpret_cast<const bf16x8*>(&bS[(ni*16 + fr) * 64 + kx]);
#pragma unroll
      for (int m2 = 0; m2 < 4; ++m2)
        af[m2] = *reinterpret_cast<const bf16x8*>(&aS[(m2*16 + fr) * 64 + kx]);
#pragma unroll
      for (int m2 = 0; m2 < 4; ++m2)
#pragma unroll
        for (int ni = 0; ni < 4; ++ni)
          acc[m2][ni] = __builtin_amdgcn_mfma_f32_16x16x32_bf16(
              af[m2], bfv[ni], acc[m2][ni], 0, 0, 0);
#pragma unroll
      for (int m2 = 0; m2 < 4; ++m2)
        af[m2] = *reinterpret_cast<const bf16x8*>(&aS[((4+m2)*16 + fr) * 64 + kx]);
#pragma unroll
      for (int m2 = 0; m2 < 4; ++m2)
#pragma unroll
        for (int ni = 0; ni < 4; ++ni)
          acc[4+m2][ni] = __builtin_amdgcn_mfma_f32_16x16x32_bf16(
              af[m2], bfv[ni], acc[4+m2][ni], 0, 0, 0);
    }
    __builtin_amdgcn_sched_barrier(0);
    __builtin_amdgcn_s_barrier();
  }

  const int lc = fr, lr4 = Lq * 4;
#pragma unroll
  for (int ni = 0; ni < 4; ++ni){
    const int col = bn*256 + wn*64 + ni*16 + lc;
    const float bv = bias ? bias[col] : 0.f;
#pragma unroll
    for (int mi = 0; mi < 8; ++mi){
      const int rowb = bm*256 + wm*128 + mi*16 + lr4;
#pragma unroll
      for (int r = 0; r < 4; ++r){
        float v = acc[mi][ni][r] + bv;
        if (RELU) v = fmaxf(v, 0.f);
        if (resid) v += resid[(size_t)(rowb + r) * N + col];
        if (OUT_BF16)
          ((unsigned short*)Cout)[(size_t)(rowb + r) * N + col] = f2bf(v);
        else
          ((float*)Cout)[(size_t)(rowb + r) * N + col] = v;
      }
    }
  }
}

// ---- bf16 MFMA GEMM, 128x128 tile, counted-vmcnt double-buffer (R5) --------
// For N=1024 GEMMs (proj, FF2): grid 8x64 = 512 blocks = 2/CU.
template<int RELU, int OUT_BF16>
__global__ __launch_bounds__(256, 2)
void gemm128ring(const unsigned short* __restrict__ A, const unsigned short* __restrict__ Bt,
                 void* __restrict__ Cout, int M, int N, int K,
                 const float* __restrict__ bias, const float* __restrict__ resid){
  __shared__ __align__(16) unsigned short As[2 * 8192];   // 32 KB
  __shared__ __align__(16) unsigned short Bs[2 * 8192];   // 32 KB
  const int tid  = threadIdx.x;
  const int wave = tid >> 6, lane = tid & 63;
  const int wm   = wave >> 1, wn = wave & 1;
  const int fr   = lane & 15, Lq = lane >> 4;

  const int id  = blockIdx.x + gridDim.x * blockIdx.y;
  const int Nbn = gridDim.x;
  const int cpx = (gridDim.x * gridDim.y) >> 3;
  const int wg  = (id & 7) * cpx + (id >> 3);
  const int bm  = wg / Nbn;
  const int bn  = wg - bm * Nbn;

  const int srow  = tid >> 3;                       // 0..31
  const int skoff = (((tid & 7) ^ (srow & 7)) * 8);
  const unsigned short* Abase = A  + (size_t)(bm * 128 + srow) * K + skoff;
  const unsigned short* Bbase = Bt + (size_t)(bn * 128 + srow) * K + skoff;

  auto stA = [&](int t){
    const unsigned short* g0 = Abase + (size_t)t * 64;
    unsigned short* l0 = As + ((t & 1) * 8192) + tid * 8;
#pragma unroll
    for (int j = 0; j < 4; ++j)
      GLD16(g0 + (size_t)(j*32) * K, l0 + j*2048);
  };
  auto stB = [&](int t){
    const unsigned short* g0 = Bbase + (size_t)t * 64;
    unsigned short* l0 = Bs + ((t & 1) * 8192) + tid * 8;
#pragma unroll
    for (int j = 0; j < 4; ++j)
      GLD16(g0 + (size_t)(j*32) * K, l0 + j*2048);
  };

  f32x4 acc[4][4] = {};
  const int NT = K >> 6;

  stA(0); stB(0);

  for (int t = 0; t < NT; ++t){
    const unsigned short* aS = As + ((t & 1) * 8192);
    const unsigned short* bS = Bs + ((t & 1) * 8192);
    const bool pf = (t + 1 < NT);

    if (pf){ stA(t+1); stB(t+1); }
    __builtin_amdgcn_sched_barrier(0);
    if (pf) asm volatile("s_waitcnt vmcnt(8)");
    else    asm volatile("s_waitcnt vmcnt(0)");
    __builtin_amdgcn_s_barrier();

#pragma unroll
    for (int kk = 0; kk < 2; ++kk){
      const int kx = (((kk*4) + Lq) ^ (fr & 7)) * 8;
      bf16x8 bfv[4], af[4];
#pragma unroll
      for (int ni = 0; ni < 4; ++ni)
        bfv[ni] = *reinterpret_cast<const bf16x8*>(&bS[(wn*64 + ni*16 + fr) * 64 + kx]);
#pragma unroll
      for (int mi = 0; mi < 4; ++mi)
        af[mi] = *reinterpret_cast<const bf16x8*>(&aS[(wm*64 + mi*16 + fr) * 64 + kx]);
#pragma unroll
      for (int mi = 0; mi < 4; ++mi)
#pragma unroll
        for (int ni = 0; ni < 4; ++ni)
          acc[mi][ni] = __builtin_amdgcn_mfma_f32_16x16x32_bf16(
              af[mi], bfv[ni], acc[mi][ni], 0, 0, 0);
    }
    __builtin_amdgcn_sched_barrier(0);
    __builtin_amdgcn_s_barrier();
  }

  const int lc = fr, lr4 = Lq * 4;
#pragma unroll
  for (int ni = 0; ni < 4; ++ni){
    const int col = bn*128 + wn*64 + ni*16 + lc;
    const float bv = bias ? bias[col] : 0.f;
#pragma unroll
    for (int mi = 0; mi < 4; ++mi){
      const int rowb = bm*128 + wm*64 + mi*16 + lr4;
#pragma unroll
      for (int r = 0; r < 4; ++r){
        float v = acc[mi][ni][r] + bv;
        if (RELU) v = fmaxf(v, 0.f);
        if (resid) v += resid[(size_t)(rowb + r) * N + col];
        if (OUT_BF16)
          ((unsigned short*)Cout)[(size_t)(rowb + r) * N + col] = f2bf(v);
        else
          ((float*)Cout)[(size_t)(rowb + r) * N + col] = v;
      }
    }
  }
}

// ---- blockify K/V from qkv into MFMA-friendly blocked global layouts -------
__global__ void blockify_kv(const unsigned short* __restrict__ qkv,
                            unsigned short* __restrict__ Kb,
                            unsigned short* __restrict__ Vb){
  const int st = blockIdx.x, h = blockIdx.y, b = blockIdx.z;
  const int tid = threadIdx.x;
  const size_t base = ((size_t)(b*Hn + h)*32 + st) * 4096;
#pragma unroll
  for (int it = 0; it < 2; ++it){
    const int idx = it*256 + tid;
    const int s = idx >> 3, d8 = idx & 7;
    const uint4 v = *reinterpret_cast<const uint4*>(
        qkv + (size_t)(b*Tn + st*64 + s)*QKVW + Cn + h*64 + d8*8);
    *reinterpret_cast<uint4*>(Kb + base + d8*512 + ((s ^ d8) * 8)) = v;
  }
#pragma unroll
  for (int it = 0; it < 2; ++it){
    const int idx = it*256 + tid;
    const int d = idx & 63, s8 = idx >> 6;
    unsigned short tmp[8];
#pragma unroll
    for (int j = 0; j < 8; ++j)
      tmp[j] = qkv[(size_t)(b*Tn + st*64 + s8*8 + j)*QKVW + 2*Cn + h*64 + d];
    ushort4 lo, hi;
    lo.x = tmp[0]; lo.y = tmp[1]; lo.z = tmp[2]; lo.w = tmp[3];
    hi.x = tmp[4]; hi.y = tmp[5]; hi.z = tmp[6]; hi.w = tmp[7];
    *reinterpret_cast<ushort4*>(Vb + base + s8*512 + ((d ^ s8) * 8))     = lo;
    *reinterpret_cast<ushort4*>(Vb + base + s8*512 + ((d ^ s8) * 8) + 4) = hi;
  }
}

// -------------------- MFMA flash attention v5 (R8: de-spill) ----------------
// R8 post-mortem: v4 spilled (live ~164 VGPR vs 128 cap -> WRITE_SIZE 69MB vs
// 16MB output). v5 keeps the de-coupled-wave structure (no barriers, direct
// L2 K/V reads) but halves register demand:
//   - 32 q-rows per wave (Oa 32 regs, qf 16) instead of 64 (Oa 64, qf 32)
//   - phase-split: K frags (32 regs) live only during QK^T+softmax; V frags
//     loaded per-db (8 regs) during PV; P round-trips through per-wave LDS.
// Peak live ~106-112 VGPR -> no spill, 4 waves/SIMD.
// Work balance: wave w of block qg owns qb in {qg, qg+16, 47-qg, 63-qg}
// (32-row q-blocks 0..63) -> every block = 66 tile-iters. Grid (64,16) =
// 1024 blocks = 4/CU, all resident. blockIdx.x = bh -> head pinned to one
// XCD's L2 (512KB K+V per head, 8 heads/XCD = 4MB).
// Addressing: granule offsets are affine in sb: off(sb) = d8*512 + sb*128 +
// (fr^d8)*8, so one 32-bit lane offset + sb*128 imm per read.
__global__ __launch_bounds__(256, 2)
void attn_mfma5(const unsigned short* __restrict__ qkv,
                const unsigned short* __restrict__ Kb,
                const unsigned short* __restrict__ Vb,
                unsigned short* __restrict__ O){
  __shared__ __align__(16) unsigned short Pt[4][2][16][72];  // [wave][f][q][s]

  const int bh = blockIdx.x;
  const int b = bh >> 4, h = bh & 15;
  const int qg = blockIdx.y;                 // 0..15
  const int tid = threadIdx.x;
  const int wv = tid >> 6, l = tid & 63;
  const int qb = (wv == 0) ? qg : (wv == 1) ? (qg + 16)
               : (wv == 2) ? (47 - qg) : (63 - qg);   // 32-row q-block, 0..63
  const int Lq = l >> 4, fr = l & 15;

  const size_t kvbase = ((size_t)(b*Hn + h) * 32) * 4096;

  union U { uint4 u; bf16x8 v; };
  // Q fragments (B-operand): lane n=fr -> q = qb*32 + f*16 + fr, f in {0,1}
  U qf[2][2];
  const unsigned short* Qbase = qkv + ((size_t)(b*Tn + qb*32)) * QKVW + h*64;
#pragma unroll
  for (int f = 0; f < 2; ++f){
    const unsigned short* qr = Qbase + (size_t)(f*16 + fr) * QKVW + Lq*8;
    qf[f][0].u = *reinterpret_cast<const uint4*>(qr);
    qf[f][1].u = *reinterpret_cast<const uint4*>(qr + 32);
  }

  f32x4 Oa[4][2] = {};                       // [db][f]
  float lsum[2] = {0.f, 0.f};
  const float C1 = 0.18033688011112042f;     // 0.125 * log2(e)
  const float C2 = 28.853900817779268f;      // 20 * log2(e) (fixed-max offset)

  // per-lane granule offsets (shorts); +sb*128 walks the s (or d) subtiles
  const int oLo = Lq*512       + ((fr ^ Lq)       * 8);
  const int oHi = (4+Lq)*512   + ((fr ^ (4+Lq))   * 8);

  const int nst = qb >> 1;                   // last s-tile for this q-block

  for (int st = 0; st <= nst; ++st){
    const unsigned short* Kt = Kb + kvbase + (size_t)st * 4096;
    const unsigned short* Vt = Vb + kvbase + (size_t)st * 4096;
    const bool diag = (st == nst);

    // ---- Phase A: K resident; QK^T + softmax for both q-frags; P -> LDS ----
    U klo[4], khi[4];
#pragma unroll
    for (int sb = 0; sb < 4; ++sb){
      klo[sb].u = *reinterpret_cast<const uint4*>(Kt + oLo + sb*128);
      khi[sb].u = *reinterpret_cast<const uint4*>(Kt + oHi + sb*128);
    }
#pragma unroll
    for (int f = 0; f < 2; ++f){
      f32x4 S[4];
#pragma unroll
      for (int sb = 0; sb < 4; ++sb){
        f32x4 z = {0.f, 0.f, 0.f, 0.f};
        z     = __builtin_amdgcn_mfma_f32_16x16x32_bf16(klo[sb].v, qf[f][0].v, z, 0, 0, 0);
        S[sb] = __builtin_amdgcn_mfma_f32_16x16x32_bf16(khi[sb].v, qf[f][1].v, z, 0, 0, 0);
      }
#pragma unroll
      for (int sb = 0; sb < 4; ++sb){
        float p0 = exp2f(fmaf(S[sb][0], C1, -C2));
        float p1 = exp2f(fmaf(S[sb][1], C1, -C2));
        float p2 = exp2f(fmaf(S[sb][2], C1, -C2));
        float p3 = exp2f(fmaf(S[sb][3], C1, -C2));
        if (diag){
          const int s0 = st*64 + sb*16 + Lq*4;     // global s of element 0
          const int q  = qb*32 + f*16 + fr;        // global q
          if (s0 + 0 > q) p0 = 0.f;
          if (s0 + 1 > q) p1 = 0.f;
          if (s0 + 2 > q) p2 = 0.f;
          if (s0 + 3 > q) p3 = 0.f;
        }
        lsum[f] += (p0 + p1) + (p2 + p3);
        const unsigned int pk0 = (unsigned int)f2bf(p0) | ((unsigned int)f2bf(p1) << 16);
        const unsigned int pk1 = (unsigned int)f2bf(p2) | ((unsigned int)f2bf(p3) << 16);
        *reinterpret_cast<uint2*>(&Pt[wv][f][fr][sb*16 + Lq*4]) = make_uint2(pk0, pk1);
      }
    }

    // ---- Phase B: V per-db (reuses the K register budget); PV ----
#pragma unroll
    for (int db = 0; db < 4; ++db){
      U vlo, vhi;
      vlo.u = *reinterpret_cast<const uint4*>(Vt + oLo + db*128);
      vhi.u = *reinterpret_cast<const uint4*>(Vt + oHi + db*128);
#pragma unroll
      for (int f = 0; f < 2; ++f){
        U pf0, pf1;
        pf0.u = *reinterpret_cast<const uint4*>(&Pt[wv][f][fr][Lq*8]);
        pf1.u = *reinterpret_cast<const uint4*>(&Pt[wv][f][fr][32 + Lq*8]);
        Oa[db][f] = __builtin_amdgcn_mfma_f32_16x16x32_bf16(vlo.v, pf0.v, Oa[db][f], 0, 0, 0);
        Oa[db][f] = __builtin_amdgcn_mfma_f32_16x16x32_bf16(vhi.v, pf1.v, Oa[db][f], 0, 0, 0);
      }
    }
  }

  // ---- epilogue: reduce l across the 4 quads holding the same q ----
#pragma unroll
  for (int f = 0; f < 2; ++f){
    float s = lsum[f];
    s += __shfl_xor(s, 16);
    s += __shfl_xor(s, 32);
    const float inv = 1.0f / s;
    const size_t orow = (size_t)(b*Tn + qb*32 + f*16 + fr);
#pragma unroll
    for (int db = 0; db < 4; ++db){
      ushort4 o;
      o.x = f2bf(Oa[db][f][0] * inv);
      o.y = f2bf(Oa[db][f][1] * inv);
      o.z = f2bf(Oa[db][f][2] * inv);
      o.w = f2bf(Oa[db][f][3] * inv);
      *reinterpret_cast<ushort4*>(&O[orow*Cn + h*64 + db*16 + Lq*4]) = o;
    }
  }
}

// -------------------- launcher ---------------------------------------------
extern "C" void kernel_launch(void* const* d_in, const int* in_sizes, int n_in,
                              void* d_out, int out_size, void* d_ws, size_t ws_size,
                              hipStream_t stream){
  const float* x     = (const float*)d_in[0];
  const float* Wq    = (const float*)d_in[1];
  const float* Wk    = (const float*)d_in[2];
  const float* Wv    = (const float*)d_in[3];
  const float* Wproj = (const float*)d_in[4];
  const float* bproj = (const float*)d_in[5];
  const float* W1    = (const float*)d_in[6];
  const float* b1    = (const float*)d_in[7];
  const float* W2    = (const float*)d_in[8];
  const float* b2    = (const float*)d_in[9];
  const float* ln1_g = (const float*)d_in[10];
  const float* ln1_b = (const float*)d_in[11];
  const float* ln2_g = (const float*)d_in[12];
  const float* ln2_b = (const float*)d_in[13];
  float* out = (float*)d_out;

  const size_t MB = 1024ull * 1024ull;
  if (ws_size < 192ull * MB){
    fprintf(stderr, "kernel_launch: need 192MB workspace, got %zu\n", ws_size);
    return;
  }
  char* ws = (char*)d_ws;
  float*          x1    = (float*)(ws + 0);
  unsigned short* h     = (unsigned short*)(ws + 32 * MB);
  unsigned short* qkvb  = (unsigned short*)(ws + 48 * MB);
  unsigned short* ff1   = (unsigned short*)(ws + 48 * MB);   // after attn
  unsigned short* Kb    = (unsigned short*)(ws + 96 * MB);
  unsigned short* Vb    = (unsigned short*)(ws + 112 * MB);
  unsigned short* Ob    = (unsigned short*)(ws + 128 * MB);
  unsigned short* Wrt   = (unsigned short*)(ws + 144 * MB);
  unsigned short* Wpt   = (unsigned short*)(ws + 150 * MB);
  unsigned short* W1t   = (unsigned short*)(ws + 152 * MB);
  unsigned short* W2t   = (unsigned short*)(ws + 160 * MB);

  // weight prep (bf16, B^T layout)
  repack_qkv_t<<<dim3(Cn/64, 3*Hn), 256, 0, stream>>>(Wq, Wk, Wv, Wrt);
  transpose_cast<<<dim3(Cn/64,  Cn/64),  256, 0, stream>>>(Wproj, Wpt, Cn,  Cn);
  transpose_cast<<<dim3(FFn/64, Cn/64),  256, 0, stream>>>(W1,    W1t, Cn,  FFn);
  transpose_cast<<<dim3(Cn/64,  FFn/64), 256, 0, stream>>>(W2,    W2t, FFn, Cn);

  // 1. h = LN1(x)  (bf16)
  ln_bf16<<<ROWS, 256, 0, stream>>>(x, ln1_g, ln1_b, h);
  // 2. qkv = h @ Wr  (bf16 out)  [256^2 counted-vmcnt]
  gemm256<0,1><<<dim3(QKVW/256, ROWS/256), 512, 0, stream>>>(
      h, Wrt, qkvb, ROWS, QKVW, Cn, nullptr, nullptr);
  // 3. blocked+swizzled K/V layouts for attention direct-read
  blockify_kv<<<dim3(Tn/64, Hn, Bn), 256, 0, stream>>>(qkvb, Kb, Vb);
  // 4. MFMA flash attention v5 (de-coupled waves, de-spilled) -> Ob
  attn_mfma5<<<dim3(64, 16), 256, 0, stream>>>(qkvb, Kb, Vb, Ob);
  // 5. x1 = x + Ob @ Wproj + bproj  (fp32)  [128^2 counted-vmcnt ring]
  gemm128ring<0,0><<<dim3(Cn/128, ROWS/128), 256, 0, stream>>>(
      Ob, Wpt, x1, ROWS, Cn, Cn, bproj, x);
  // 6. h2 = LN2(x1)  (bf16)
  ln_bf16<<<ROWS, 256, 0, stream>>>(x1, ln2_g, ln2_b, h);
  // 7. ff1 = relu(h2 @ W1 + b1)  (bf16)  [256^2 counted-vmcnt]
  gemm256<1,1><<<dim3(FFn/256, ROWS/256), 512, 0, stream>>>(
      h, W1t, ff1, ROWS, FFn, Cn, b1, nullptr);
  // 8. out = x1 + ff1 @ W2 + b2  (fp32)  [128^2 counted-vmcnt ring]
  gemm128ring<0,0><<<dim3(Cn/128, ROWS/128), 256, 0, stream>>>(
      ff1, W2t, out, ROWS, Cn, FFn, b2, x1);
}

// Round 10
// 534.222 us; speedup vs baseline: 1.0963x; 1.0467x over previous
//
#include <hip/hip_runtime.h>
#include <cstddef>
#include <cstdio>

// Problem constants: B=4, T=2048, C=1024, H=16, HS=64, FF=4096
#define Bn   4
#define Tn   2048
#define Cn   1024
#define Hn   16
#define HSn  64
#define FFn  4096
#define ROWS (Bn*Tn)        // 8192
#define QKVW (3*Cn)         // 3072

typedef __attribute__((ext_vector_type(8))) __bf16 bf16x8;
typedef __attribute__((ext_vector_type(4))) float f32x4;

// fp32 -> bf16 round-to-nearest-even, raw ushort storage
__device__ __forceinline__ unsigned short f2bf(float f){
  unsigned int u = __float_as_uint(f);
  unsigned int r = (u + 0x7fffu + ((u >> 16) & 1u)) >> 16;
  return (unsigned short)r;
}

// async global->LDS, 16B per lane; LDS dest = wave-uniform base + lane*16
#define GLD16(g, l) __builtin_amdgcn_global_load_lds( \
    (__attribute__((address_space(1))) void*)(void*)(g), \
    (__attribute__((address_space(3))) void*)(l), 16, 0, 0)

__device__ __forceinline__ float wave_sum_f(float v){
#pragma unroll
  for (int o = 32; o > 0; o >>= 1) v += __shfl_xor(v, o);
  return v;
}

// -------------------- LayerNorm: fp32 in -> bf16 out, one block per row -----
__global__ void ln_bf16(const float* __restrict__ x, const float* __restrict__ g,
                        const float* __restrict__ bb, unsigned short* __restrict__ y){
  const int row = blockIdx.x;
  const int tid = threadIdx.x;
  const float4 v = reinterpret_cast<const float4*>(x + (size_t)row * Cn)[tid];
  float s  = v.x + v.y + v.z + v.w;
  float ss = v.x*v.x + v.y*v.y + v.z*v.z + v.w*v.w;
  s = wave_sum_f(s); ss = wave_sum_f(ss);
  __shared__ float sm[4], sm2[4];
  const int w = tid >> 6, lane = tid & 63;
  if (lane == 0){ sm[w] = s; sm2[w] = ss; }
  __syncthreads();
  const float tot  = sm[0] + sm[1] + sm[2] + sm[3];
  const float tot2 = sm2[0] + sm2[1] + sm2[2] + sm2[3];
  const float mu = tot * (1.0f / Cn);
  const float rs = rsqrtf(tot2 * (1.0f / Cn) - mu * mu + 1e-5f);
  const float4 gv = reinterpret_cast<const float4*>(g)[tid];
  const float4 bv = reinterpret_cast<const float4*>(bb)[tid];
  ushort4 o;
  o.x = f2bf((v.x - mu) * rs * gv.x + bv.x);
  o.y = f2bf((v.y - mu) * rs * gv.y + bv.y);
  o.z = f2bf((v.z - mu) * rs * gv.z + bv.z);
  o.w = f2bf((v.w - mu) * rs * gv.w + bv.w);
  reinterpret_cast<ushort4*>(y + (size_t)row * Cn)[tid] = o;
}

// ---- generic transpose+cast: in fp32 [R][Cc] -> out bf16 [Cc][R] -----------
__global__ void transpose_cast(const float* __restrict__ in, unsigned short* __restrict__ out,
                               int R, int Cc){
  __shared__ float t[64][65];
  const int tid = threadIdx.x;
  const int r0 = blockIdx.y * 64, c0 = blockIdx.x * 64;
  const int rb = tid >> 6, cl = tid & 63;
#pragma unroll
  for (int j = 0; j < 16; ++j)
    t[rb + j*4][cl] = in[(size_t)(r0 + rb + j*4) * Cc + c0 + cl];
  __syncthreads();
#pragma unroll
  for (int j = 0; j < 16; ++j)
    out[(size_t)(c0 + rb + j*4) * R + r0 + cl] = f2bf(t[cl][rb + j*4]);
}

// ---- QKV weights [H,C,HS] -> Wrt bf16 [N=3C][K=C]; row j = sec*C + h*64 + d
__global__ void repack_qkv_t(const float* __restrict__ Wq, const float* __restrict__ Wk,
                             const float* __restrict__ Wv, unsigned short* __restrict__ Wrt){
  __shared__ float t[64][65];
  const int tid = threadIdx.x;
  const int kb = blockIdx.x * 64;            // k tile
  const int hh = blockIdx.y;                 // 0..47
  const int sec = hh >> 4, h = hh & 15;
  const float* W = (sec == 0) ? Wq : ((sec == 1) ? Wk : Wv);
  const int rb = tid >> 6, dl = tid & 63;
#pragma unroll
  for (int j = 0; j < 16; ++j)
    t[rb + j*4][dl] = W[h * (Cn*HSn) + (size_t)(kb + rb + j*4) * HSn + dl];
  __syncthreads();
#pragma unroll
  for (int j = 0; j < 16; ++j)
    Wrt[(size_t)(sec*Cn + h*64 + rb + j*4) * Cn + kb + dl] = f2bf(t[dl][rb + j*4]);
}

// ---- bf16 MFMA GEMM, 256x256 tile, counted-vmcnt ring pipeline -------------
// (R4-verified.)  512 threads = 8 waves (2M x 4N), per-wave 128x64 out.
// BK=64. 4-slot ring of 16KB half-tiles per operand; tile t -> slots
// {2t,2t+1}&3. Per K-tile: stage t+1 (8 GLD16) -> vmcnt(8) -> barrier
// -> 64 MFMA -> barrier.  Swizzle: granule (row,k8) holds global k8^(row&7);
// read applies same XOR.  Grid: bijective XCD remap (nwg % 8 == 0).
template<int RELU, int OUT_BF16>
__global__ __launch_bounds__(512, 2)
void gemm256(const unsigned short* __restrict__ A, const unsigned short* __restrict__ Bt,
             void* __restrict__ Cout, int M, int N, int K,
             const float* __restrict__ bias, const float* __restrict__ resid){
  __shared__ __align__(16) unsigned short As[4 * 8192];   // 64 KB
  __shared__ __align__(16) unsigned short Bs[4 * 8192];   // 64 KB
  const int tid  = threadIdx.x;
  const int wid  = tid >> 6, lane = tid & 63;
  const int wm   = wid >> 2, wn = wid & 3;
  const int fr   = lane & 15, Lq = lane >> 4;

  const int id  = blockIdx.x + gridDim.x * blockIdx.y;
  const int Nbn = gridDim.x;
  const int cpx = (gridDim.x * gridDim.y) >> 3;
  const int wg  = (id & 7) * cpx + (id >> 3);
  const int bm  = wg / Nbn;
  const int bn  = wg - bm * Nbn;

  const int srow  = wid * 8 + (lane >> 3);
  const int skoff = (((lane & 7) ^ (srow & 7)) * 8);
  const unsigned short* Abase = A  + (size_t)(bm * 256 + srow) * K + skoff;
  const unsigned short* Bbase = Bt + (size_t)(bn * 256 + srow) * K + skoff;

  auto stA = [&](int t, int h){
    const unsigned short* g0 = Abase + (size_t)h * 128 * K + (size_t)t * 64;
    unsigned short* l0 = As + (((2*t + h) & 3) * 8192) + wid * 512;
    GLD16(g0, l0);
    GLD16(g0 + (size_t)64 * K, l0 + 4096);
  };
  auto stB = [&](int t, int h){
    const unsigned short* g0 = Bbase + (size_t)h * 128 * K + (size_t)t * 64;
    unsigned short* l0 = Bs + (((2*t + h) & 3) * 8192) + wid * 512;
    GLD16(g0, l0);
    GLD16(g0 + (size_t)64 * K, l0 + 4096);
  };

  f32x4 acc[8][4] = {};
  const int NT = K >> 6;

  stA(0, 0); stA(0, 1); stB(0, 0); stB(0, 1);

  for (int t = 0; t < NT; ++t){
    const unsigned short* aS = As + (((2*t + wm) & 3) * 8192);
    const unsigned short* bS = Bs + (((2*t + (wn >> 1)) & 3) * 8192)
                                  + ((wn & 1) * 64) * 64;
    const bool pf = (t + 1 < NT);

    if (pf){ stA(t+1, 0); stA(t+1, 1); stB(t+1, 0); stB(t+1, 1); }
    __builtin_amdgcn_sched_barrier(0);
    if (pf) asm volatile("s_waitcnt vmcnt(8)");
    else    asm volatile("s_waitcnt vmcnt(0)");
    __builtin_amdgcn_s_barrier();

#pragma unroll
    for (int kk = 0; kk < 2; ++kk){
      const int kx = (((kk*4) + Lq) ^ (fr & 7)) * 8;
      bf16x8 bfv[4], af[4];
#pragma unroll
      for (int ni = 0; ni < 4; ++ni)
        bfv[ni] = *reinterpret_cast<const bf16x8*>(&bS[(ni*16 + fr) * 64 + kx]);
#pragma unroll
      for (int m2 = 0; m2 < 4; ++m2)
        af[m2] = *reinterpret_cast<const bf16x8*>(&aS[(m2*16 + fr) * 64 + kx]);
#pragma unroll
      for (int m2 = 0; m2 < 4; ++m2)
#pragma unroll
        for (int ni = 0; ni < 4; ++ni)
          acc[m2][ni] = __builtin_amdgcn_mfma_f32_16x16x32_bf16(
              af[m2], bfv[ni], acc[m2][ni], 0, 0, 0);
#pragma unroll
      for (int m2 = 0; m2 < 4; ++m2)
        af[m2] = *reinterpret_cast<const bf16x8*>(&aS[((4+m2)*16 + fr) * 64 + kx]);
#pragma unroll
      for (int m2 = 0; m2 < 4; ++m2)
#pragma unroll
        for (int ni = 0; ni < 4; ++ni)
          acc[4+m2][ni] = __builtin_amdgcn_mfma_f32_16x16x32_bf16(
              af[m2], bfv[ni], acc[4+m2][ni], 0, 0, 0);
    }
    __builtin_amdgcn_sched_barrier(0);
    __builtin_amdgcn_s_barrier();
  }

  const int lc = fr, lr4 = Lq * 4;
#pragma unroll
  for (int ni = 0; ni < 4; ++ni){
    const int col = bn*256 + wn*64 + ni*16 + lc;
    const float bv = bias ? bias[col] : 0.f;
#pragma unroll
    for (int mi = 0; mi < 8; ++mi){
      const int rowb = bm*256 + wm*128 + mi*16 + lr4;
#pragma unroll
      for (int r = 0; r < 4; ++r){
        float v = acc[mi][ni][r] + bv;
        if (RELU) v = fmaxf(v, 0.f);
        if (resid) v += resid[(size_t)(rowb + r) * N + col];
        if (OUT_BF16)
          ((unsigned short*)Cout)[(size_t)(rowb + r) * N + col] = f2bf(v);
        else
          ((float*)Cout)[(size_t)(rowb + r) * N + col] = v;
      }
    }
  }
}

// ---- bf16 MFMA GEMM, 128x128 tile, counted-vmcnt double-buffer (R5) --------
// For N=1024 GEMMs (proj, FF2): grid 8x64 = 512 blocks = 2/CU.
template<int RELU, int OUT_BF16>
__global__ __launch_bounds__(256, 2)
void gemm128ring(const unsigned short* __restrict__ A, const unsigned short* __restrict__ Bt,
                 void* __restrict__ Cout, int M, int N, int K,
                 const float* __restrict__ bias, const float* __restrict__ resid){
  __shared__ __align__(16) unsigned short As[2 * 8192];   // 32 KB
  __shared__ __align__(16) unsigned short Bs[2 * 8192];   // 32 KB
  const int tid  = threadIdx.x;
  const int wave = tid >> 6, lane = tid & 63;
  const int wm   = wave >> 1, wn = wave & 1;
  const int fr   = lane & 15, Lq = lane >> 4;

  const int id  = blockIdx.x + gridDim.x * blockIdx.y;
  const int Nbn = gridDim.x;
  const int cpx = (gridDim.x * gridDim.y) >> 3;
  const int wg  = (id & 7) * cpx + (id >> 3);
  const int bm  = wg / Nbn;
  const int bn  = wg - bm * Nbn;

  const int srow  = tid >> 3;                       // 0..31
  const int skoff = (((tid & 7) ^ (srow & 7)) * 8);
  const unsigned short* Abase = A  + (size_t)(bm * 128 + srow) * K + skoff;
  const unsigned short* Bbase = Bt + (size_t)(bn * 128 + srow) * K + skoff;

  auto stA = [&](int t){
    const unsigned short* g0 = Abase + (size_t)t * 64;
    unsigned short* l0 = As + ((t & 1) * 8192) + tid * 8;
#pragma unroll
    for (int j = 0; j < 4; ++j)
      GLD16(g0 + (size_t)(j*32) * K, l0 + j*2048);
  };
  auto stB = [&](int t){
    const unsigned short* g0 = Bbase + (size_t)t * 64;
    unsigned short* l0 = Bs + ((t & 1) * 8192) + tid * 8;
#pragma unroll
    for (int j = 0; j < 4; ++j)
      GLD16(g0 + (size_t)(j*32) * K, l0 + j*2048);
  };

  f32x4 acc[4][4] = {};
  const int NT = K >> 6;

  stA(0); stB(0);

  for (int t = 0; t < NT; ++t){
    const unsigned short* aS = As + ((t & 1) * 8192);
    const unsigned short* bS = Bs + ((t & 1) * 8192);
    const bool pf = (t + 1 < NT);

    if (pf){ stA(t+1); stB(t+1); }
    __builtin_amdgcn_sched_barrier(0);
    if (pf) asm volatile("s_waitcnt vmcnt(8)");
    else    asm volatile("s_waitcnt vmcnt(0)");
    __builtin_amdgcn_s_barrier();

#pragma unroll
    for (int kk = 0; kk < 2; ++kk){
      const int kx = (((kk*4) + Lq) ^ (fr & 7)) * 8;
      bf16x8 bfv[4], af[4];
#pragma unroll
      for (int ni = 0; ni < 4; ++ni)
        bfv[ni] = *reinterpret_cast<const bf16x8*>(&bS[(wn*64 + ni*16 + fr) * 64 + kx]);
#pragma unroll
      for (int mi = 0; mi < 4; ++mi)
        af[mi] = *reinterpret_cast<const bf16x8*>(&aS[(wm*64 + mi*16 + fr) * 64 + kx]);
#pragma unroll
      for (int mi = 0; mi < 4; ++mi)
#pragma unroll
        for (int ni = 0; ni < 4; ++ni)
          acc[mi][ni] = __builtin_amdgcn_mfma_f32_16x16x32_bf16(
              af[mi], bfv[ni], acc[mi][ni], 0, 0, 0);
    }
    __builtin_amdgcn_sched_barrier(0);
    __builtin_amdgcn_s_barrier();
  }

  const int lc = fr, lr4 = Lq * 4;
#pragma unroll
  for (int ni = 0; ni < 4; ++ni){
    const int col = bn*128 + wn*64 + ni*16 + lc;
    const float bv = bias ? bias[col] : 0.f;
#pragma unroll
    for (int mi = 0; mi < 4; ++mi){
      const int rowb = bm*128 + wm*64 + mi*16 + lr4;
#pragma unroll
      for (int r = 0; r < 4; ++r){
        float v = acc[mi][ni][r] + bv;
        if (RELU) v = fmaxf(v, 0.f);
        if (resid) v += resid[(size_t)(rowb + r) * N + col];
        if (OUT_BF16)
          ((unsigned short*)Cout)[(size_t)(rowb + r) * N + col] = f2bf(v);
        else
          ((float*)Cout)[(size_t)(rowb + r) * N + col] = v;
      }
    }
  }
}

// ---- blockify K/V from qkv into MFMA-friendly blocked global layouts -------
__global__ void blockify_kv(const unsigned short* __restrict__ qkv,
                            unsigned short* __restrict__ Kb,
                            unsigned short* __restrict__ Vb){
  const int st = blockIdx.x, h = blockIdx.y, b = blockIdx.z;
  const int tid = threadIdx.x;
  const size_t base = ((size_t)(b*Hn + h)*32 + st) * 4096;
#pragma unroll
  for (int it = 0; it < 2; ++it){
    const int idx = it*256 + tid;
    const int s = idx >> 3, d8 = idx & 7;
    const uint4 v = *reinterpret_cast<const uint4*>(
        qkv + (size_t)(b*Tn + st*64 + s)*QKVW + Cn + h*64 + d8*8);
    *reinterpret_cast<uint4*>(Kb + base + d8*512 + ((s ^ d8) * 8)) = v;
  }
#pragma unroll
  for (int it = 0; it < 2; ++it){
    const int idx = it*256 + tid;
    const int d = idx & 63, s8 = idx >> 6;
    unsigned short tmp[8];
#pragma unroll
    for (int j = 0; j < 8; ++j)
      tmp[j] = qkv[(size_t)(b*Tn + st*64 + s8*8 + j)*QKVW + 2*Cn + h*64 + d];
    ushort4 lo, hi;
    lo.x = tmp[0]; lo.y = tmp[1]; lo.z = tmp[2]; lo.w = tmp[3];
    hi.x = tmp[4]; hi.y = tmp[5]; hi.z = tmp[6]; hi.w = tmp[7];
    *reinterpret_cast<ushort4*>(Vb + base + s8*512 + ((d ^ s8) * 8))     = lo;
    *reinterpret_cast<ushort4*>(Vb + base + s8*512 + ((d ^ s8) * 8) + 4) = hi;
  }
}

// -------------------- MFMA flash attention v6 (R9: balance) -----------------
// R9 post-mortem: v5 de-spilled (VGPR 68, WRITE 16MB) but stayed at 116us
// because per-SIMD work was unbalanced: wave wv of every block owned q-blocks
// {qg, qg+16, 47-qg, 63-qg} -> wave 3 always heavy (up to 32 tile-iters),
// wave 0 always light (1-8); wave i lands on SIMD i, so one SIMD/CU carried
// ~4x28 iters while others idled (VALUBusy 43% avg, critical SIMD saturated).
// v6: complementary-pair scheduling. Each wave sequentially processes TWO
// 32-row q-blocks (p, 63-p) whose tile counts sum to exactly 33 for every p
// -> every wave in the machine has identical work; per-SIMD balance is exact.
// Per-pass body is byte-identical to v5 (same masking/offsets/epilogue).
// Grid (64 bh, 8 qg) x 256 thr; p = qg*4+wv in 0..31. Head -> XCD L2 pinning
// unchanged (bh%8).
__global__ __launch_bounds__(256, 2)
void attn_mfma6(const unsigned short* __restrict__ qkv,
                const unsigned short* __restrict__ Kb,
                const unsigned short* __restrict__ Vb,
                unsigned short* __restrict__ O){
  __shared__ __align__(16) unsigned short Pt[4][2][16][72];  // [wave][f][q][s]

  const int bh = blockIdx.x;
  const int b = bh >> 4, h = bh & 15;
  const int qg = blockIdx.y;                 // 0..7
  const int tid = threadIdx.x;
  const int wv = tid >> 6, l = tid & 63;
  const int p  = qg*4 + wv;                  // pair id 0..31
  const int Lq = l >> 4, fr = l & 15;

  const size_t kvbase = ((size_t)(b*Hn + h) * 32) * 4096;

  union U { uint4 u; bf16x8 v; };
  const float C1 = 0.18033688011112042f;     // 0.125 * log2(e)
  const float C2 = 28.853900817779268f;      // 20 * log2(e) (fixed-max offset)

  // per-lane granule offsets (shorts); +sb*128 walks the s (or d) subtiles
  const int oLo = Lq*512       + ((fr ^ Lq)       * 8);
  const int oHi = (4+Lq)*512   + ((fr ^ (4+Lq))   * 8);

  for (int pass = 0; pass < 2; ++pass){
    const int qb = pass ? (63 - p) : p;      // 32-row q-block, 0..63

    // Q fragments (B-operand): lane n=fr -> q = qb*32 + f*16 + fr
    U qf[2][2];
    const unsigned short* Qbase = qkv + ((size_t)(b*Tn + qb*32)) * QKVW + h*64;
#pragma unroll
    for (int f = 0; f < 2; ++f){
      const unsigned short* qr = Qbase + (size_t)(f*16 + fr) * QKVW + Lq*8;
      qf[f][0].u = *reinterpret_cast<const uint4*>(qr);
      qf[f][1].u = *reinterpret_cast<const uint4*>(qr + 32);
    }

    f32x4 Oa[4][2] = {};                     // [db][f]
    float lsum[2] = {0.f, 0.f};
    const int nst = qb >> 1;                 // last s-tile for this q-block

    for (int st = 0; st <= nst; ++st){
      const unsigned short* Kt = Kb + kvbase + (size_t)st * 4096;
      const unsigned short* Vt = Vb + kvbase + (size_t)st * 4096;
      const bool diag = (st == nst);

      // ---- Phase A: K resident; QK^T + softmax both q-frags; P -> LDS ----
      U klo[4], khi[4];
#pragma unroll
      for (int sb = 0; sb < 4; ++sb){
        klo[sb].u = *reinterpret_cast<const uint4*>(Kt + oLo + sb*128);
        khi[sb].u = *reinterpret_cast<const uint4*>(Kt + oHi + sb*128);
      }
#pragma unroll
      for (int f = 0; f < 2; ++f){
        f32x4 S[4];
#pragma unroll
        for (int sb = 0; sb < 4; ++sb){
          f32x4 z = {0.f, 0.f, 0.f, 0.f};
          z     = __builtin_amdgcn_mfma_f32_16x16x32_bf16(klo[sb].v, qf[f][0].v, z, 0, 0, 0);
          S[sb] = __builtin_amdgcn_mfma_f32_16x16x32_bf16(khi[sb].v, qf[f][1].v, z, 0, 0, 0);
        }
#pragma unroll
        for (int sb = 0; sb < 4; ++sb){
          float p0 = exp2f(fmaf(S[sb][0], C1, -C2));
          float p1 = exp2f(fmaf(S[sb][1], C1, -C2));
          float p2 = exp2f(fmaf(S[sb][2], C1, -C2));
          float p3 = exp2f(fmaf(S[sb][3], C1, -C2));
          if (diag){
            const int s0 = st*64 + sb*16 + Lq*4;   // global s of element 0
            const int q  = qb*32 + f*16 + fr;      // global q
            if (s0 + 0 > q) p0 = 0.f;
            if (s0 + 1 > q) p1 = 0.f;
            if (s0 + 2 > q) p2 = 0.f;
            if (s0 + 3 > q) p3 = 0.f;
          }
          lsum[f] += (p0 + p1) + (p2 + p3);
          const unsigned int pk0 = (unsigned int)f2bf(p0) | ((unsigned int)f2bf(p1) << 16);
          const unsigned int pk1 = (unsigned int)f2bf(p2) | ((unsigned int)f2bf(p3) << 16);
          *reinterpret_cast<uint2*>(&Pt[wv][f][fr][sb*16 + Lq*4]) = make_uint2(pk0, pk1);
        }
      }

      // ---- Phase B: V per-db (reuses the K register budget); PV ----
#pragma unroll
      for (int db = 0; db < 4; ++db){
        U vlo, vhi;
        vlo.u = *reinterpret_cast<const uint4*>(Vt + oLo + db*128);
        vhi.u = *reinterpret_cast<const uint4*>(Vt + oHi + db*128);
#pragma unroll
        for (int f = 0; f < 2; ++f){
          U pf0, pf1;
          pf0.u = *reinterpret_cast<const uint4*>(&Pt[wv][f][fr][Lq*8]);
          pf1.u = *reinterpret_cast<const uint4*>(&Pt[wv][f][fr][32 + Lq*8]);
          Oa[db][f] = __builtin_amdgcn_mfma_f32_16x16x32_bf16(vlo.v, pf0.v, Oa[db][f], 0, 0, 0);
          Oa[db][f] = __builtin_amdgcn_mfma_f32_16x16x32_bf16(vhi.v, pf1.v, Oa[db][f], 0, 0, 0);
        }
      }
    }

    // ---- epilogue: reduce l across the 4 quads holding the same q ----
#pragma unroll
    for (int f = 0; f < 2; ++f){
      float s = lsum[f];
      s += __shfl_xor(s, 16);
      s += __shfl_xor(s, 32);
      const float inv = 1.0f / s;
      const size_t orow = (size_t)(b*Tn + qb*32 + f*16 + fr);
#pragma unroll
      for (int db = 0; db < 4; ++db){
        ushort4 o;
        o.x = f2bf(Oa[db][f][0] * inv);
        o.y = f2bf(Oa[db][f][1] * inv);
        o.z = f2bf(Oa[db][f][2] * inv);
        o.w = f2bf(Oa[db][f][3] * inv);
        *reinterpret_cast<ushort4*>(&O[orow*Cn + h*64 + db*16 + Lq*4]) = o;
      }
    }
  }
}

// -------------------- launcher ---------------------------------------------
extern "C" void kernel_launch(void* const* d_in, const int* in_sizes, int n_in,
                              void* d_out, int out_size, void* d_ws, size_t ws_size,
                              hipStream_t stream){
  const float* x     = (const float*)d_in[0];
  const float* Wq    = (const float*)d_in[1];
  const float* Wk    = (const float*)d_in[2];
  const float* Wv    = (const float*)d_in[3];
  const float* Wproj = (const float*)d_in[4];
  const float* bproj = (const float*)d_in[5];
  const float* W1    = (const float*)d_in[6];
  const float* b1    = (const float*)d_in[7];
  const float* W2    = (const float*)d_in[8];
  const float* b2    = (const float*)d_in[9];
  const float* ln1_g = (const float*)d_in[10];
  const float* ln1_b = (const float*)d_in[11];
  const float* ln2_g = (const float*)d_in[12];
  const float* ln2_b = (const float*)d_in[13];
  float* out = (float*)d_out;

  const size_t MB = 1024ull * 1024ull;
  if (ws_size < 192ull * MB){
    fprintf(stderr, "kernel_launch: need 192MB workspace, got %zu\n", ws_size);
    return;
  }
  char* ws = (char*)d_ws;
  float*          x1    = (float*)(ws + 0);
  unsigned short* h     = (unsigned short*)(ws + 32 * MB);
  unsigned short* qkvb  = (unsigned short*)(ws + 48 * MB);
  unsigned short* ff1   = (unsigned short*)(ws + 48 * MB);   // after attn
  unsigned short* Kb    = (unsigned short*)(ws + 96 * MB);
  unsigned short* Vb    = (unsigned short*)(ws + 112 * MB);
  unsigned short* Ob    = (unsigned short*)(ws + 128 * MB);
  unsigned short* Wrt   = (unsigned short*)(ws + 144 * MB);
  unsigned short* Wpt   = (unsigned short*)(ws + 150 * MB);
  unsigned short* W1t   = (unsigned short*)(ws + 152 * MB);
  unsigned short* W2t   = (unsigned short*)(ws + 160 * MB);

  // weight prep (bf16, B^T layout)
  repack_qkv_t<<<dim3(Cn/64, 3*Hn), 256, 0, stream>>>(Wq, Wk, Wv, Wrt);
  transpose_cast<<<dim3(Cn/64,  Cn/64),  256, 0, stream>>>(Wproj, Wpt, Cn,  Cn);
  transpose_cast<<<dim3(FFn/64, Cn/64),  256, 0, stream>>>(W1,    W1t, Cn,  FFn);
  transpose_cast<<<dim3(Cn/64,  FFn/64), 256, 0, stream>>>(W2,    W2t, FFn, Cn);

  // 1. h = LN1(x)  (bf16)
  ln_bf16<<<ROWS, 256, 0, stream>>>(x, ln1_g, ln1_b, h);
  // 2. qkv = h @ Wr  (bf16 out)  [256^2 counted-vmcnt]
  gemm256<0,1><<<dim3(QKVW/256, ROWS/256), 512, 0, stream>>>(
      h, Wrt, qkvb, ROWS, QKVW, Cn, nullptr, nullptr);
  // 3. blocked+swizzled K/V layouts for attention direct-read
  blockify_kv<<<dim3(Tn/64, Hn, Bn), 256, 0, stream>>>(qkvb, Kb, Vb);
  // 4. MFMA flash attention v6 (complementary-pair balanced) -> Ob
  attn_mfma6<<<dim3(64, 8), 256, 0, stream>>>(qkvb, Kb, Vb, Ob);
  // 5. x1 = x + Ob @ Wproj + bproj  (fp32)  [128^2 counted-vmcnt ring]
  gemm128ring<0,0><<<dim3(Cn/128, ROWS/128), 256, 0, stream>>>(
      Ob, Wpt, x1, ROWS, Cn, Cn, bproj, x);
  // 6. h2 = LN2(x1)  (bf16)
  ln_bf16<<<ROWS, 256, 0, stream>>>(x1, ln2_g, ln2_b, h);
  // 7. ff1 = relu(h2 @ W1 + b1)  (bf16)  [256^2 counted-vmcnt]
  gemm256<1,1><<<dim3(FFn/256, ROWS/256), 512, 0, stream>>>(
      h, W1t, ff1, ROWS, FFn, Cn, b1, nullptr);
  // 8. out = x1 + ff1 @ W2 + b2  (fp32)  [128^2 counted-vmcnt ring]
  gemm128ring<0,0><<<dim3(Cn/128, ROWS/128), 256, 0, stream>>>(
      ff1, W2t, out, ROWS, Cn, FFn, b2, x1);
}